// Round 1
// baseline (941.078 us; speedup 1.0000x reference)
//
#include <hip/hip_runtime.h>
#include <hip/hip_bf16.h>
#include <math.h>

// Problem constants (B, La, Lb, D) from reference setup_inputs()
#define NB 32
#define LA 512
#define LB 512
#define DD 768

// ---------------------------------------------------------------------------
// Kernel 1: E[b,i,j] = sum_d A[b,i,d] * Bm[b,j,d]   (NT GEMM, fp32)
// 64x64 tile, K-step 16, 256 threads, 4x4 accum per thread.
// ---------------------------------------------------------------------------
__global__ __launch_bounds__(256) void gemm_e_kernel(
    const float* __restrict__ A, const float* __restrict__ Bm,
    float* __restrict__ E) {
  const int b = blockIdx.z;
  const int i0 = blockIdx.x * 64;
  const int j0 = blockIdx.y * 64;
  const float* Ab = A + (size_t)b * LA * DD;
  const float* Bb = Bm + (size_t)b * LB * DD;
  float* Eb = E + (size_t)b * LA * LB;

  __shared__ float As[16][68];  // [k][i], padded stride 68 to spread banks
  __shared__ float Bs[16][68];  // [k][j]

  const int t = threadIdx.x;
  const int tx = t & 15;   // N (j) group
  const int ty = t >> 4;   // M (i) group
  const int lr = t >> 2;   // load row 0..63
  const int lc = t & 3;    // load float4 chunk 0..3 (covers k=16)

  float acc[4][4] = {{0.f}};

  for (int k0 = 0; k0 < DD; k0 += 16) {
    const float4 av = *(const float4*)(Ab + (size_t)(i0 + lr) * DD + k0 + lc * 4);
    const float4 bv = *(const float4*)(Bb + (size_t)(j0 + lr) * DD + k0 + lc * 4);
    __syncthreads();
    As[lc * 4 + 0][lr] = av.x; As[lc * 4 + 1][lr] = av.y;
    As[lc * 4 + 2][lr] = av.z; As[lc * 4 + 3][lr] = av.w;
    Bs[lc * 4 + 0][lr] = bv.x; Bs[lc * 4 + 1][lr] = bv.y;
    Bs[lc * 4 + 2][lr] = bv.z; Bs[lc * 4 + 3][lr] = bv.w;
    __syncthreads();
#pragma unroll
    for (int k = 0; k < 16; ++k) {
      const float4 a4 = *(const float4*)&As[k][ty * 4];
      const float4 b4 = *(const float4*)&Bs[k][tx * 4];
      const float ar[4] = {a4.x, a4.y, a4.z, a4.w};
      const float br[4] = {b4.x, b4.y, b4.z, b4.w};
#pragma unroll
      for (int r = 0; r < 4; ++r)
#pragma unroll
        for (int c = 0; c < 4; ++c) acc[r][c] += ar[r] * br[c];
    }
  }

#pragma unroll
  for (int r = 0; r < 4; ++r) {
    const float4 v = make_float4(acc[r][0], acc[r][1], acc[r][2], acc[r][3]);
    *(float4*)(Eb + (size_t)(i0 + ty * 4 + r) * LB + j0 + tx * 4) = v;
  }
}

// ---------------------------------------------------------------------------
// Kernel 2: per-row (axis=2) softmax stats: rmax[b,i], rsum[b,i]
// One wave (64 lanes) per row; 4 rows per 256-thread block.
// ---------------------------------------------------------------------------
__global__ __launch_bounds__(256) void row_stats_kernel(
    const float* __restrict__ E, float* __restrict__ rmax,
    float* __restrict__ rsum) {
  const int wave = threadIdx.x >> 6;
  const int lane = threadIdx.x & 63;
  const int row = blockIdx.x * 4 + wave;  // 0 .. NB*LA-1
  const float* Er = E + (size_t)row * LB;

  float vals[8];
  float m = -INFINITY;
#pragma unroll
  for (int c = 0; c < 8; ++c) {
    vals[c] = Er[lane + c * 64];
    m = fmaxf(m, vals[c]);
  }
#pragma unroll
  for (int off = 32; off > 0; off >>= 1) m = fmaxf(m, __shfl_xor(m, off));
  float s = 0.f;
#pragma unroll
  for (int c = 0; c < 8; ++c) s += __expf(vals[c] - m);
#pragma unroll
  for (int off = 32; off > 0; off >>= 1) s += __shfl_xor(s, off);
  if (lane == 0) {
    rmax[row] = m;
    rsum[row] = s;
  }
}

// ---------------------------------------------------------------------------
// Kernel 3: per-column (axis=1) softmax stats: cmax[b,j], csum[b,j]
// One thread per column, online softmax; coalesced row sweeps.
// ---------------------------------------------------------------------------
__global__ __launch_bounds__(256) void col_stats_kernel(
    const float* __restrict__ E, float* __restrict__ cmax,
    float* __restrict__ csum) {
  const int b = blockIdx.y;
  const int j = blockIdx.x * 256 + threadIdx.x;
  const float* Eb = E + (size_t)b * LA * LB;
  float m = -INFINITY, s = 0.f;
  for (int i = 0; i < LA; ++i) {
    const float v = Eb[(size_t)i * LB + j];
    const float mn = fmaxf(m, v);
    s = s * __expf(m - mn) + __expf(v - mn);
    m = mn;
  }
  cmax[b * LB + j] = m;
  csum[b * LB + j] = s;
}

// ---------------------------------------------------------------------------
// Kernel 4: a_tilde[i,d] = sum_j softmax_row(E)[i,j] * Bm[j,d], fused m_a write
// ---------------------------------------------------------------------------
__global__ __launch_bounds__(256) void gemm_at_kernel(
    const float* __restrict__ E, const float* __restrict__ Bm,
    const float* __restrict__ A, const float* __restrict__ rmax,
    const float* __restrict__ rsum, float* __restrict__ Ma) {
  const int b = blockIdx.z;
  const int i0 = blockIdx.x * 64;  // M tile (i)
  const int d0 = blockIdx.y * 64;  // N tile (d)
  const float* Eb = E + (size_t)b * LA * LB;
  const float* Bb = Bm + (size_t)b * LB * DD;

  __shared__ float Ps[16][68];  // [k=j][i] : exp(e - rmax[i])
  __shared__ float Bs[16][68];  // [k=j][d]
  __shared__ float rm[64], rs[64];

  const int t = threadIdx.x;
  const int tx = t & 15;
  const int ty = t >> 4;
  const int lr = t >> 2;  // E load: row i0+lr
  const int lc = t & 3;   // E load: k chunk
  const int br = t >> 4;  // B load: row k0+br
  const int bc = t & 15;  // B load: d chunk

  if (t < 64) {
    rm[t] = rmax[b * LA + i0 + t];
    rs[t] = 1.f / rsum[b * LA + i0 + t];
  }
  __syncthreads();

  float acc[4][4] = {{0.f}};

  for (int k0 = 0; k0 < LB; k0 += 16) {
    const float4 ev = *(const float4*)(Eb + (size_t)(i0 + lr) * LB + k0 + lc * 4);
    const float4 bv = *(const float4*)(Bb + (size_t)(k0 + br) * DD + d0 + bc * 4);
    const float rmv = rm[lr];
    __syncthreads();
    Ps[lc * 4 + 0][lr] = __expf(ev.x - rmv);
    Ps[lc * 4 + 1][lr] = __expf(ev.y - rmv);
    Ps[lc * 4 + 2][lr] = __expf(ev.z - rmv);
    Ps[lc * 4 + 3][lr] = __expf(ev.w - rmv);
    *(float4*)&Bs[br][bc * 4] = bv;
    __syncthreads();
#pragma unroll
    for (int k = 0; k < 16; ++k) {
      const float4 a4 = *(const float4*)&Ps[k][ty * 4];
      const float4 b4 = *(const float4*)&Bs[k][tx * 4];
      const float ar[4] = {a4.x, a4.y, a4.z, a4.w};
      const float br2[4] = {b4.x, b4.y, b4.z, b4.w};
#pragma unroll
      for (int r = 0; r < 4; ++r)
#pragma unroll
        for (int c = 0; c < 4; ++c) acc[r][c] += ar[r] * br2[c];
    }
  }

#pragma unroll
  for (int r = 0; r < 4; ++r) {
    const int i = i0 + ty * 4 + r;
    const float sc = rs[ty * 4 + r];
    const int d = d0 + tx * 4;
    const float4 av = *(const float4*)(A + ((size_t)b * LA + i) * DD + d);
    float4 at = make_float4(acc[r][0] * sc, acc[r][1] * sc, acc[r][2] * sc,
                            acc[r][3] * sc);
    float* base = Ma + ((size_t)b * LA + i) * (4 * DD);
    *(float4*)(base + d) = av;
    *(float4*)(base + DD + d) = at;
    *(float4*)(base + 2 * DD + d) =
        make_float4(av.x - at.x, av.y - at.y, av.z - at.z, av.w - at.w);
    *(float4*)(base + 3 * DD + d) =
        make_float4(av.x * at.x, av.y * at.y, av.z * at.z, av.w * at.w);
  }
}

// ---------------------------------------------------------------------------
// Kernel 5: b_tilde[j,d] = sum_i softmax_col(E)[i,j] * A[i,d], fused m_b write
// ---------------------------------------------------------------------------
__global__ __launch_bounds__(256) void gemm_bt_kernel(
    const float* __restrict__ E, const float* __restrict__ A,
    const float* __restrict__ Bm, const float* __restrict__ cmax,
    const float* __restrict__ csum, float* __restrict__ Mb) {
  const int b = blockIdx.z;
  const int j0 = blockIdx.x * 64;  // M tile (j)
  const int d0 = blockIdx.y * 64;  // N tile (d)
  const float* Eb = E + (size_t)b * LA * LB;
  const float* Ab = A + (size_t)b * LA * DD;

  __shared__ float Ps[16][68];  // [k=i][j] : exp(e - cmax[j])
  __shared__ float As[16][68];  // [k=i][d]
  __shared__ float cm[64], cs[64];

  const int t = threadIdx.x;
  const int tx = t & 15;
  const int ty = t >> 4;
  const int er = t >> 4;  // E/A load: row k0+er
  const int ec = t & 15;  // E load: j chunk / A load: d chunk

  if (t < 64) {
    cm[t] = cmax[b * LB + j0 + t];
    cs[t] = 1.f / csum[b * LB + j0 + t];
  }
  __syncthreads();

  float acc[4][4] = {{0.f}};

  for (int k0 = 0; k0 < LA; k0 += 16) {
    const float4 ev = *(const float4*)(Eb + (size_t)(k0 + er) * LB + j0 + ec * 4);
    const float4 av = *(const float4*)(Ab + (size_t)(k0 + er) * DD + d0 + ec * 4);
    const float4 cmv = *(const float4*)&cm[ec * 4];
    __syncthreads();
    Ps[er][ec * 4 + 0] = __expf(ev.x - cmv.x);
    Ps[er][ec * 4 + 1] = __expf(ev.y - cmv.y);
    Ps[er][ec * 4 + 2] = __expf(ev.z - cmv.z);
    Ps[er][ec * 4 + 3] = __expf(ev.w - cmv.w);
    *(float4*)&As[er][ec * 4] = av;
    __syncthreads();
#pragma unroll
    for (int k = 0; k < 16; ++k) {
      const float4 a4 = *(const float4*)&Ps[k][ty * 4];
      const float4 b4 = *(const float4*)&As[k][tx * 4];
      const float ar[4] = {a4.x, a4.y, a4.z, a4.w};
      const float br2[4] = {b4.x, b4.y, b4.z, b4.w};
#pragma unroll
      for (int r = 0; r < 4; ++r)
#pragma unroll
        for (int c = 0; c < 4; ++c) acc[r][c] += ar[r] * br2[c];
    }
  }

#pragma unroll
  for (int r = 0; r < 4; ++r) {
    const int j = j0 + ty * 4 + r;
    const float sc = cs[ty * 4 + r];
    const int d = d0 + tx * 4;
    const float4 bv = *(const float4*)(Bm + ((size_t)b * LB + j) * DD + d);
    float4 bt = make_float4(acc[r][0] * sc, acc[r][1] * sc, acc[r][2] * sc,
                            acc[r][3] * sc);
    float* base = Mb + ((size_t)b * LB + j) * (4 * DD);
    *(float4*)(base + d) = bv;
    *(float4*)(base + DD + d) = bt;
    *(float4*)(base + 2 * DD + d) =
        make_float4(bv.x - bt.x, bv.y - bt.y, bv.z - bt.z, bv.w - bt.w);
    *(float4*)(base + 3 * DD + d) =
        make_float4(bv.x * bt.x, bv.y * bt.y, bv.z * bt.z, bv.w * bt.w);
  }
}

// ---------------------------------------------------------------------------
extern "C" void kernel_launch(void* const* d_in, const int* in_sizes, int n_in,
                              void* d_out, int out_size, void* d_ws,
                              size_t ws_size, hipStream_t stream) {
  const float* a = (const float*)d_in[0];   // [32, 512, 768]
  const float* bb = (const float*)d_in[1];  // [32, 512, 768]
  float* out = (float*)d_out;
  float* Ma = out;                                   // [32, 512, 3072]
  float* Mb = out + (size_t)NB * LA * 4 * DD;        // [32, 512, 3072]

  // workspace layout: E (33.5 MB) + 4 stat arrays (64 KB each)
  float* E = (float*)d_ws;
  float* rmax = (float*)((char*)d_ws + (size_t)NB * LA * LB * sizeof(float));
  float* rsum = rmax + NB * LA;
  float* cmax = rsum + NB * LA;
  float* csum = cmax + NB * LB;

  gemm_e_kernel<<<dim3(LA / 64, LB / 64, NB), 256, 0, stream>>>(a, bb, E);
  row_stats_kernel<<<dim3(NB * LA / 4), 256, 0, stream>>>(E, rmax, rsum);
  col_stats_kernel<<<dim3(LB / 256, NB), 256, 0, stream>>>(E, cmax, csum);
  gemm_at_kernel<<<dim3(LA / 64, DD / 64, NB), 256, 0, stream>>>(E, bb, a, rmax,
                                                                 rsum, Ma);
  gemm_bt_kernel<<<dim3(LB / 64, DD / 64, NB), 256, 0, stream>>>(E, a, bb, cmax,
                                                                 csum, Mb);
}

// Round 2
// 653.675 us; speedup vs baseline: 1.4397x; 1.4397x over previous
//
#include <hip/hip_runtime.h>
#include <hip/hip_bf16.h>
#include <math.h>

#define NB 32
#define LA 512
#define LB 512
#define DD 768

typedef __bf16 bf16x4 __attribute__((ext_vector_type(4)));
typedef __bf16 bf16x8 __attribute__((ext_vector_type(8)));
typedef float f32x4 __attribute__((ext_vector_type(4)));

// LDS row stride for bf16 tiles: 32 k + 8 pad = 40 bf16 = 80 B (16B-aligned rows)
#define LSTR 40

// ---------------------------------------------------------------------------
// Kernel 1: E = A·B^T in split-bf16 MFMA (3 passes: hh + hl + lh).
// 128x128 tile, BK=32, 256 thr = 4 waves (2x2 of 64x64), mfma 16x16x32.
// ---------------------------------------------------------------------------
__global__ __launch_bounds__(256) void gemm_e_mfma(
    const float* __restrict__ A, const float* __restrict__ Bm,
    float* __restrict__ E) {
  __shared__ __bf16 Ah[128][LSTR], Al[128][LSTR];
  __shared__ __bf16 Bh[128][LSTR], Bl[128][LSTR];

  const int b = blockIdx.z;
  const int i0 = blockIdx.x * 128, j0 = blockIdx.y * 128;
  const float* Ab = A + (size_t)b * LA * DD;
  const float* Bb = Bm + (size_t)b * LB * DD;
  float* Eb = E + (size_t)b * LA * LB;

  const int t = threadIdx.x;
  const int lane = t & 63, wave = t >> 6;
  const int wm = (wave >> 1) * 64, wn = (wave & 1) * 64;
  const int quad = lane >> 4, l16 = lane & 15;
  const int sr = t >> 3, sc = t & 7;  // staging: 32 rows/pass, 8 k-chunks

  f32x4 acc[4][4] = {};

  for (int k0 = 0; k0 < DD; k0 += 32) {
    float4 av[4], bv[4];
#pragma unroll
    for (int p = 0; p < 4; ++p) {
      av[p] = *(const float4*)(Ab + (size_t)(i0 + sr + p * 32) * DD + k0 + sc * 4);
      bv[p] = *(const float4*)(Bb + (size_t)(j0 + sr + p * 32) * DD + k0 + sc * 4);
    }
    __syncthreads();
#pragma unroll
    for (int p = 0; p < 4; ++p) {
      const int m = sr + p * 32;
      float va[4] = {av[p].x, av[p].y, av[p].z, av[p].w};
      float vb[4] = {bv[p].x, bv[p].y, bv[p].z, bv[p].w};
      bf16x4 ha, la, hb, lb;
#pragma unroll
      for (int q = 0; q < 4; ++q) {
        __bf16 h = (__bf16)va[q];
        ha[q] = h; la[q] = (__bf16)(va[q] - (float)h);
        h = (__bf16)vb[q];
        hb[q] = h; lb[q] = (__bf16)(vb[q] - (float)h);
      }
      *(bf16x4*)&Ah[m][sc * 4] = ha; *(bf16x4*)&Al[m][sc * 4] = la;
      *(bf16x4*)&Bh[m][sc * 4] = hb; *(bf16x4*)&Bl[m][sc * 4] = lb;
    }
    __syncthreads();

    bf16x8 fah[4], fal[4], fbh[4], fbl[4];
#pragma unroll
    for (int f = 0; f < 4; ++f) {
      fah[f] = *(bf16x8*)&Ah[wm + f * 16 + l16][quad * 8];
      fal[f] = *(bf16x8*)&Al[wm + f * 16 + l16][quad * 8];
      fbh[f] = *(bf16x8*)&Bh[wn + f * 16 + l16][quad * 8];
      fbl[f] = *(bf16x8*)&Bl[wn + f * 16 + l16][quad * 8];
    }
#pragma unroll
    for (int fm = 0; fm < 4; ++fm)
#pragma unroll
      for (int fn = 0; fn < 4; ++fn) {
        acc[fm][fn] = __builtin_amdgcn_mfma_f32_16x16x32_bf16(fah[fm], fbh[fn], acc[fm][fn], 0, 0, 0);
        acc[fm][fn] = __builtin_amdgcn_mfma_f32_16x16x32_bf16(fah[fm], fbl[fn], acc[fm][fn], 0, 0, 0);
        acc[fm][fn] = __builtin_amdgcn_mfma_f32_16x16x32_bf16(fal[fm], fbh[fn], acc[fm][fn], 0, 0, 0);
      }
  }

#pragma unroll
  for (int fm = 0; fm < 4; ++fm)
#pragma unroll
    for (int r = 0; r < 4; ++r) {
      const int i = i0 + wm + fm * 16 + quad * 4 + r;
#pragma unroll
      for (int fn = 0; fn < 4; ++fn)
        Eb[(size_t)i * LB + j0 + wn + fn * 16 + l16] = acc[fm][fn][r];
    }
}

// ---------------------------------------------------------------------------
// Kernel 2: row softmax stats (axis=2)
// ---------------------------------------------------------------------------
__global__ __launch_bounds__(256) void row_stats_kernel(
    const float* __restrict__ E, float* __restrict__ rmax,
    float* __restrict__ rsum) {
  const int wave = threadIdx.x >> 6;
  const int lane = threadIdx.x & 63;
  const int row = blockIdx.x * 4 + wave;
  const float* Er = E + (size_t)row * LB;
  float vals[8];
  float m = -INFINITY;
#pragma unroll
  for (int c = 0; c < 8; ++c) {
    vals[c] = Er[lane + c * 64];
    m = fmaxf(m, vals[c]);
  }
#pragma unroll
  for (int off = 32; off > 0; off >>= 1) m = fmaxf(m, __shfl_xor(m, off));
  float s = 0.f;
#pragma unroll
  for (int c = 0; c < 8; ++c) s += __expf(vals[c] - m);
#pragma unroll
  for (int off = 32; off > 0; off >>= 1) s += __shfl_xor(s, off);
  if (lane == 0) { rmax[row] = m; rsum[row] = s; }
}

// ---------------------------------------------------------------------------
// Kernel 3: column softmax stats (axis=1)
// ---------------------------------------------------------------------------
__global__ __launch_bounds__(256) void col_stats_kernel(
    const float* __restrict__ E, float* __restrict__ cmax,
    float* __restrict__ csum) {
  const int b = blockIdx.y;
  const int j = blockIdx.x * 256 + threadIdx.x;
  const float* Eb = E + (size_t)b * LA * LB;
  float m = -INFINITY, s = 0.f;
  for (int i = 0; i < LA; ++i) {
    const float v = Eb[(size_t)i * LB + j];
    const float mn = fmaxf(m, v);
    s = s * __expf(m - mn) + __expf(v - mn);
    m = mn;
  }
  cmax[b * LB + j] = m;
  csum[b * LB + j] = s;
}

// ---------------------------------------------------------------------------
// Kernel 4: a_tilde = softmax_row(E)·B, bf16 MFMA, fused m_a epilogue.
// M=i(512) N=d(768) K=j(512), tile 128x128x32.
// ---------------------------------------------------------------------------
__global__ __launch_bounds__(256) void gemm_at_mfma(
    const float* __restrict__ E, const float* __restrict__ Bm,
    const float* __restrict__ A, const float* __restrict__ rmax,
    const float* __restrict__ rsum, float* __restrict__ Ma) {
  __shared__ __bf16 Ps[128][LSTR];   // [i][j]  P = exp(e-rm)*rsinv
  __shared__ __bf16 Bs[128][LSTR];   // [d][j]  transposed B
  __shared__ float rm_s[128], rs_s[128];

  const int b = blockIdx.z;
  const int i0 = blockIdx.x * 128, d0 = blockIdx.y * 128;
  const float* Eb = E + (size_t)b * LA * LB;
  const float* Bb = Bm + (size_t)b * LB * DD;
  const float* Ab = A + (size_t)b * LA * DD;

  const int t = threadIdx.x;
  const int lane = t & 63, wave = t >> 6;
  const int wm = (wave >> 1) * 64, wn = (wave & 1) * 64;
  const int quad = lane >> 4, l16 = lane & 15;
  const int sr = t >> 3, sc = t & 7;   // P staging
  const int jr = t >> 3, jc = t & 7;   // B staging: j-row group, d-chunk

  if (t < 128) {
    rm_s[t] = rmax[b * LA + i0 + t];
    rs_s[t] = 1.f / rsum[b * LA + i0 + t];
  }
  __syncthreads();

  f32x4 acc[4][4] = {};

  for (int k0 = 0; k0 < LB; k0 += 32) {
    float4 ev[4], bv[4];
#pragma unroll
    for (int p = 0; p < 4; ++p) {
      ev[p] = *(const float4*)(Eb + (size_t)(i0 + sr + p * 32) * LB + k0 + sc * 4);
      // B rows k0+jr (32 j's), d-cols d0 + p*32 + jc*4
      bv[p] = *(const float4*)(Bb + (size_t)(k0 + jr) * DD + d0 + p * 32 + jc * 4);
    }
    __syncthreads();
#pragma unroll
    for (int p = 0; p < 4; ++p) {
      const int m = sr + p * 32;
      const float rmv = rm_s[m], rsv = rs_s[m];
      float v[4] = {ev[p].x, ev[p].y, ev[p].z, ev[p].w};
      bf16x4 pb;
#pragma unroll
      for (int q = 0; q < 4; ++q) pb[q] = (__bf16)(__expf(v[q] - rmv) * rsv);
      *(bf16x4*)&Ps[m][sc * 4] = pb;
      // transpose-write B: Bs[d][j]
      float w[4] = {bv[p].x, bv[p].y, bv[p].z, bv[p].w};
#pragma unroll
      for (int q = 0; q < 4; ++q) Bs[p * 32 + jc * 4 + q][jr] = (__bf16)w[q];
    }
    __syncthreads();

    bf16x8 fa[4], fb[4];
#pragma unroll
    for (int f = 0; f < 4; ++f) {
      fa[f] = *(bf16x8*)&Ps[wm + f * 16 + l16][quad * 8];
      fb[f] = *(bf16x8*)&Bs[wn + f * 16 + l16][quad * 8];
    }
#pragma unroll
    for (int fm = 0; fm < 4; ++fm)
#pragma unroll
      for (int fn = 0; fn < 4; ++fn)
        acc[fm][fn] = __builtin_amdgcn_mfma_f32_16x16x32_bf16(fa[fm], fb[fn], acc[fm][fn], 0, 0, 0);
  }

#pragma unroll
  for (int fm = 0; fm < 4; ++fm)
#pragma unroll
    for (int r = 0; r < 4; ++r) {
      const int i = i0 + wm + fm * 16 + quad * 4 + r;
      float* base = Ma + ((size_t)b * LA + i) * (4 * DD);
#pragma unroll
      for (int fn = 0; fn < 4; ++fn) {
        const int d = d0 + wn + fn * 16 + l16;
        const float av = Ab[(size_t)i * DD + d];
        const float at = acc[fm][fn][r];
        base[d] = av;
        base[DD + d] = at;
        base[2 * DD + d] = av - at;
        base[3 * DD + d] = av * at;
      }
    }
}

// ---------------------------------------------------------------------------
// Kernel 5: b_tilde = softmax_col(E)^T·A, bf16 MFMA, fused m_b epilogue.
// M=j(512) N=d(768) K=i(512), tile 128x128x32. Both operands transposed stage.
// ---------------------------------------------------------------------------
__global__ __launch_bounds__(256) void gemm_bt_mfma(
    const float* __restrict__ E, const float* __restrict__ A,
    const float* __restrict__ Bm, const float* __restrict__ cmax,
    const float* __restrict__ csum, float* __restrict__ Mb) {
  __shared__ __bf16 Ps[128][LSTR];   // [j][i]  P2 = exp(e-cm)*csinv
  __shared__ __bf16 As[128][LSTR];   // [d][i]  transposed A
  __shared__ float cm_s[128], cs_s[128];

  const int b = blockIdx.z;
  const int j0 = blockIdx.x * 128, d0 = blockIdx.y * 128;
  const float* Eb = E + (size_t)b * LA * LB;
  const float* Ab = A + (size_t)b * LA * DD;
  const float* Bb = Bm + (size_t)b * LB * DD;

  const int t = threadIdx.x;
  const int lane = t & 63, wave = t >> 6;
  const int wm = (wave >> 1) * 64, wn = (wave & 1) * 64;
  const int quad = lane >> 4, l16 = lane & 15;
  const int ir = t >> 3, ic = t & 7;  // staging: i-row group (32), col chunk

  if (t < 128) {
    cm_s[t] = cmax[b * LB + j0 + t];
    cs_s[t] = 1.f / csum[b * LB + j0 + t];
  }
  __syncthreads();

  f32x4 acc[4][4] = {};

  for (int k0 = 0; k0 < LA; k0 += 32) {
    float4 ev[4], av[4];
#pragma unroll
    for (int p = 0; p < 4; ++p) {
      // E rows k0+ir (32 i's), j-cols j0 + p*32 + ic*4
      ev[p] = *(const float4*)(Eb + (size_t)(k0 + ir) * LB + j0 + p * 32 + ic * 4);
      // A rows k0+ir, d-cols d0 + p*32 + ic*4
      av[p] = *(const float4*)(Ab + (size_t)(k0 + ir) * DD + d0 + p * 32 + ic * 4);
    }
    __syncthreads();
#pragma unroll
    for (int p = 0; p < 4; ++p) {
      const float4 cm4 = *(const float4*)&cm_s[p * 32 + ic * 4];
      const float4 cs4 = *(const float4*)&cs_s[p * 32 + ic * 4];
      float v[4] = {ev[p].x, ev[p].y, ev[p].z, ev[p].w};
      float cmv[4] = {cm4.x, cm4.y, cm4.z, cm4.w};
      float csv[4] = {cs4.x, cs4.y, cs4.z, cs4.w};
      float w[4] = {av[p].x, av[p].y, av[p].z, av[p].w};
#pragma unroll
      for (int q = 0; q < 4; ++q) {
        Ps[p * 32 + ic * 4 + q][ir] = (__bf16)(__expf(v[q] - cmv[q]) * csv[q]);
        As[p * 32 + ic * 4 + q][ir] = (__bf16)w[q];
      }
    }
    __syncthreads();

    bf16x8 fa[4], fb[4];
#pragma unroll
    for (int f = 0; f < 4; ++f) {
      fa[f] = *(bf16x8*)&Ps[wm + f * 16 + l16][quad * 8];
      fb[f] = *(bf16x8*)&As[wn + f * 16 + l16][quad * 8];
    }
#pragma unroll
    for (int fm = 0; fm < 4; ++fm)
#pragma unroll
      for (int fn = 0; fn < 4; ++fn)
        acc[fm][fn] = __builtin_amdgcn_mfma_f32_16x16x32_bf16(fa[fm], fb[fn], acc[fm][fn], 0, 0, 0);
  }

#pragma unroll
  for (int fm = 0; fm < 4; ++fm)
#pragma unroll
    for (int r = 0; r < 4; ++r) {
      const int j = j0 + wm + fm * 16 + quad * 4 + r;
      float* base = Mb + ((size_t)b * LB + j) * (4 * DD);
#pragma unroll
      for (int fn = 0; fn < 4; ++fn) {
        const int d = d0 + wn + fn * 16 + l16;
        const float bvv = Bb[(size_t)j * DD + d];
        const float bt = acc[fm][fn][r];
        base[d] = bvv;
        base[DD + d] = bt;
        base[2 * DD + d] = bvv - bt;
        base[3 * DD + d] = bvv * bt;
      }
    }
}

// ---------------------------------------------------------------------------
extern "C" void kernel_launch(void* const* d_in, const int* in_sizes, int n_in,
                              void* d_out, int out_size, void* d_ws,
                              size_t ws_size, hipStream_t stream) {
  const float* a = (const float*)d_in[0];
  const float* bb = (const float*)d_in[1];
  float* out = (float*)d_out;
  float* Ma = out;
  float* Mb = out + (size_t)NB * LA * 4 * DD;

  float* E = (float*)d_ws;
  float* rmax = (float*)((char*)d_ws + (size_t)NB * LA * LB * sizeof(float));
  float* rsum = rmax + NB * LA;
  float* cmax = rsum + NB * LA;
  float* csum = cmax + NB * LB;

  gemm_e_mfma<<<dim3(LA / 128, LB / 128, NB), 256, 0, stream>>>(a, bb, E);
  row_stats_kernel<<<dim3(NB * LA / 4), 256, 0, stream>>>(E, rmax, rsum);
  col_stats_kernel<<<dim3(LB / 256, NB), 256, 0, stream>>>(E, cmax, csum);
  gemm_at_mfma<<<dim3(LA / 128, DD / 128, NB), 256, 0, stream>>>(E, bb, a, rmax,
                                                                 rsum, Ma);
  gemm_bt_mfma<<<dim3(LB / 128, DD / 128, NB), 256, 0, stream>>>(E, a, bb, cmax,
                                                                 csum, Mb);
}